// Round 9
// baseline (135.197 us; speedup 1.0000x reference)
//
#include <hip/hip_runtime.h>
#include <hip/hip_bf16.h>
#include <math.h>

#define SCALE 0.125f
#define EPS 1e-5f
#define LN_EPS 1e-5f

typedef short short8 __attribute__((ext_vector_type(8)));
typedef float floatx4 __attribute__((ext_vector_type(4)));
typedef unsigned short us;

__device__ __forceinline__ float elu1(float x) { return x > 0.f ? x + 1.f : __expf(x); }
__device__ __forceinline__ us f2bf(float f) {
    __hip_bfloat16 b = __float2bfloat16(f);
    return __builtin_bit_cast(us, b);
}
__device__ __forceinline__ void gload_lds16(const void* g, void* lds) {
    __builtin_amdgcn_global_load_lds(
        (const __attribute__((address_space(1))) unsigned int*)g,
        (__attribute__((address_space(3))) unsigned int*)lds, 16, 0, 0);
}
__device__ __forceinline__ floatx4 mfma_bf16(short8 a, short8 b, floatx4 c) {
    return __builtin_amdgcn_mfma_f32_16x16x32_bf16(a, b, c, 0, 0, 0);
}

// ---------------- pack: h->bf16, weight transposes, VTg ones ---------------
// WqkvT row layout: [0..511]=Wq cols; [512..1535]= per-head K_h(64)|V_h(64).
__global__ __launch_bounds__(256)
void pack_kernel(const float* __restrict__ h, const float* __restrict__ Wq,
                 const float* __restrict__ Wkv, const float* __restrict__ Wo,
                 us* __restrict__ hB, us* __restrict__ WqkvT, us* __restrict__ WoT,
                 us* __restrict__ VTg) {
    const int bid = blockIdx.x, tid = threadIdx.x;
    if (bid < 2048) {
        int idx = bid * 1024 + tid * 4;
        float4 v = *(const float4*)(h + idx);
        ushort4 o;
        o.x = f2bf(v.x); o.y = f2bf(v.y); o.z = f2bf(v.z); o.w = f2bf(v.w);
        *(ushort4*)(hB + idx) = o;
        return;
    }
    if (bid < 2304) {
        __shared__ us T[64][72];
        const float* src; int ld, n0s, k0; us* dst;
        if (bid < 2240) {
            int t2 = bid - 2048;           // Wqkv: 24 n-tiles x 8 k-tiles
            int nt = t2 % 24, kt = t2 / 24;
            k0 = kt * 64;
            if (nt < 8) { src = Wq; ld = 512; n0s = nt * 64; }
            else {
                int t = nt - 8, hh = t >> 1, half = t & 1;
                src = Wkv; ld = 1024;
                n0s = half ? 512 + hh * 64 : hh * 64;   // K half | V half
            }
            dst = WqkvT + (size_t)(nt * 64) * 512;
        } else {
            int t2 = bid - 2240;           // Wo: 8 x 8
            int nt = t2 & 7, kt = t2 >> 3;
            src = Wo; ld = 512; n0s = nt * 64; k0 = kt * 64;
            dst = WoT + (size_t)(nt * 64) * 512;
        }
        {
            int k = tid >> 2, cs = (tid & 3) * 16;
            const float* p = src + (size_t)(k0 + k) * ld + n0s + cs;
#pragma unroll
            for (int q = 0; q < 4; ++q) {
                float4 v = *(const float4*)(p + q * 4);
                T[k][cs + q * 4 + 0] = f2bf(v.x);
                T[k][cs + q * 4 + 1] = f2bf(v.y);
                T[k][cs + q * 4 + 2] = f2bf(v.z);
                T[k][cs + q * 4 + 3] = f2bf(v.w);
            }
        }
        __syncthreads();
        {
            int n = tid >> 2, ks = (tid & 3) * 16;
            __align__(16) us tmp[16];
#pragma unroll
            for (int j = 0; j < 16; ++j) tmp[j] = T[ks + j][n];
            us* po = dst + (size_t)n * 512 + k0 + ks;
            *(uint4*)(po) = *(uint4*)(tmp);
            *(uint4*)(po + 8) = *(uint4*)(tmp + 8);
        }
        return;
    }
    {   // VTg ones row (row 64 of each chain)
        int e = (bid - 2304) * 1024 + tid * 4;
        int chain = e >> 11, s = e & 2047;
        ushort4 o; o.x = 0x3f80; o.y = 0x3f80; o.z = 0x3f80; o.w = 0x3f80;
        *(ushort4*)(VTg + ((size_t)(chain * 80 + 64)) * 2048 + s) = o;
    }
}

// ---------------- QKV GEMM (BM=128, dbuf) + fused chunk-KV epilogue --------
union QkvSmem {
    struct { us As[2][128 * 32]; us Bs[2][128 * 32]; } st;  // 32 KB
    us ET[128 * 130];                                       // 33.25 KB
};

__global__ __launch_bounds__(256)
void qkv_gemm(const us* __restrict__ A, const us* __restrict__ BT,
              us* __restrict__ Qg, us* __restrict__ Kg, us* __restrict__ VTg,
              float* __restrict__ KVc) {
    __shared__ QkvSmem sm;
    const int tid = threadIdx.x;
    const int w = tid >> 6, l = tid & 63;
    const int l15 = l & 15, l4 = l >> 4;
    const int ntile = blockIdx.x, c = blockIdx.y;
    const int m0 = c * 128, n0 = ntile * 128;
    const int wm = (w >> 1) * 64, wn = (w & 1) * 64;
    floatx4 acc[4][4];
#pragma unroll
    for (int i = 0; i < 4; ++i)
#pragma unroll
        for (int j = 0; j < 4; ++j)
#pragma unroll
            for (int e = 0; e < 4; ++e) acc[i][j][e] = 0.f;

    auto STAGE = [&](int buf, int kt) {
#pragma unroll
        for (int r = 0; r < 2; ++r) {
            int slot = (r * 4 + w) * 64 + l;
            int row = slot >> 2, part = slot & 3;
            int g = part ^ (row & 3);
            gload_lds16(A + (size_t)(m0 + row) * 512 + kt + g * 8,
                        &sm.st.As[buf][(r * 4 + w) * 512]);
            gload_lds16(BT + (size_t)(n0 + row) * 512 + kt + g * 8,
                        &sm.st.Bs[buf][(r * 4 + w) * 512]);
        }
    };
    STAGE(0, 0);
    __syncthreads();
    for (int t = 0; t < 16; ++t) {
        int cur = t & 1;
        if (t < 15) STAGE(cur ^ 1, (t + 1) * 32);
        short8 a[4], b[4];
#pragma unroll
        for (int mi = 0; mi < 4; ++mi) {
            int row = wm + mi * 16 + l15;
            int p = l4 ^ (row & 3);
            a[mi] = *(const short8*)(&sm.st.As[cur][row * 32 + p * 8]);
        }
#pragma unroll
        for (int ni = 0; ni < 4; ++ni) {
            int row = wn + ni * 16 + l15;
            int p = l4 ^ (row & 3);
            b[ni] = *(const short8*)(&sm.st.Bs[cur][row * 32 + p * 8]);
        }
#pragma unroll
        for (int mi = 0; mi < 4; ++mi)
#pragma unroll
            for (int ni = 0; ni < 4; ++ni)
                acc[mi][ni] = mfma_bf16(a[mi], b[ni], acc[mi][ni]);
        __syncthreads();
    }

    if (ntile < 4) {
        // Q region: elu, row-major
        const int cb = ntile * 128;
#pragma unroll
        for (int mi = 0; mi < 4; ++mi)
#pragma unroll
            for (int ni = 0; ni < 4; ++ni)
#pragma unroll
                for (int r = 0; r < 4; ++r) {
                    int row = m0 + wm + mi * 16 + l4 * 4 + r;
                    int col = cb + wn + ni * 16 + l15;
                    Qg[(size_t)row * 512 + col] = f2bf(elu1(acc[mi][ni][r]));
                }
        return;
    }

    // KV tile for head h: cols 0-63 = K_h (waves w&1==0), 64-127 = V_h.
    const int h = ntile - 4;
    if ((w & 1) == 0) {
        // K: elu, row-major into Kg
#pragma unroll
        for (int mi = 0; mi < 4; ++mi)
#pragma unroll
            for (int ni = 0; ni < 4; ++ni)
#pragma unroll
                for (int r = 0; r < 4; ++r) {
                    int row = m0 + wm + mi * 16 + l4 * 4 + r;
                    Kg[(size_t)row * 512 + h * 64 + ni * 16 + l15] =
                        f2bf(elu1(acc[mi][ni][r]));
                }
    } else {
        // V: transposed packed into VTg[chain][d][s]
#pragma unroll
        for (int mi = 0; mi < 4; ++mi) {
            int base = m0 + wm + mi * 16 + l4 * 4;  // global row, %4==0
            int s0 = base >> 1;                      // even
#pragma unroll
            for (int ni = 0; ni < 4; ++ni) {
                int dd = ni * 16 + l15;
                unsigned int pk0 = (unsigned int)f2bf(acc[mi][ni][0]) |
                                   ((unsigned int)f2bf(acc[mi][ni][2]) << 16);
                unsigned int pk1 = (unsigned int)f2bf(acc[mi][ni][1]) |
                                   ((unsigned int)f2bf(acc[mi][ni][3]) << 16);
                *(unsigned int*)(VTg + ((size_t)(h * 80 + dd)) * 2048 + s0) = pk0;
                *(unsigned int*)(VTg + ((size_t)((8 + h) * 80 + dd)) * 2048 + s0) = pk1;
            }
        }
    }

    // deposit tile into ET[d][s + 64*b] (batch de-interleaved), K cols elu'd
#pragma unroll
    for (int mi = 0; mi < 4; ++mi) {
        int row0 = wm + mi * 16 + l4 * 4;  // local row, %4==0
        int s0 = row0 >> 1;                 // even
#pragma unroll
        for (int ni = 0; ni < 4; ++ni) {
            int d = wn + ni * 16 + l15;
            float v0 = acc[mi][ni][0], v1 = acc[mi][ni][1];
            float v2 = acc[mi][ni][2], v3 = acc[mi][ni][3];
            if (d < 64) { v0 = elu1(v0); v1 = elu1(v1); v2 = elu1(v2); v3 = elu1(v3); }
            unsigned int w0 = (unsigned int)f2bf(v0) | ((unsigned int)f2bf(v2) << 16);
            unsigned int w1 = (unsigned int)f2bf(v1) | ((unsigned int)f2bf(v3) << 16);
            *(unsigned int*)(sm.ET + d * 130 + s0) = w0;        // b=0: s0,s0+1
            *(unsigned int*)(sm.ET + d * 130 + 64 + s0) = w1;   // b=1
        }
    }
    __syncthreads();

    // chunk-KV outer product per batch: KVc[chain][c] = [V^T;1] @ K^T
    short8 ones8, zero8;
#pragma unroll
    for (int e = 0; e < 8; ++e) { ones8[e] = (short)0x3f80; zero8[e] = 0; }
#pragma unroll 1
    for (int b = 0; b < 2; ++b) {
        const int off = b * 64;
        short8 af[5][2], bfr[2];
#pragma unroll
        for (int mi = 0; mi < 4; ++mi) {
            int dv = mi * 16 + l15;
            af[mi][0] = *(const short8*)(sm.ET + (64 + dv) * 130 + off + l4 * 8);
            af[mi][1] = *(const short8*)(sm.ET + (64 + dv) * 130 + off + 32 + l4 * 8);
        }
        af[4][0] = (l15 == 0) ? ones8 : zero8;
        af[4][1] = af[4][0];
        {
            int dk = w * 16 + l15;
            bfr[0] = *(const short8*)(sm.ET + dk * 130 + off + l4 * 8);
            bfr[1] = *(const short8*)(sm.ET + dk * 130 + off + 32 + l4 * 8);
        }
        float* outkv = KVc + (size_t)((b * 8 + h) * 32 + c) * 4608;
#pragma unroll
        for (int mi = 0; mi < 5; ++mi) {
            floatx4 a = {0.f, 0.f, 0.f, 0.f};
            a = mfma_bf16(af[mi][0], bfr[0], a);
            a = mfma_bf16(af[mi][1], bfr[1], a);
#pragma unroll
            for (int r = 0; r < 4; ++r) {
                int row = mi * 16 + l4 * 4 + r;
                if (row < 65) outkv[row * 64 + w * 16 + l15] = a[r];
            }
        }
    }
}

// ---------------- exclusive prefix over chunks -> bf16 MTg -----------------
__global__ __launch_bounds__(256)
void cumsum_kernel(const float* __restrict__ KVc, us* __restrict__ MTg) {
    const int chain = blockIdx.x, rg = blockIdx.y;
    const int row = rg * 4 + (threadIdx.x >> 6), col = threadIdx.x & 63;
    const float* in = KVc + (size_t)chain * 32 * 4608 + row * 64 + col;
    us* out = MTg + ((size_t)chain * 32 * 80 + row) * 64 + col;
    float acc = 0.f;
#pragma unroll 4
    for (int cc = 0; cc < 32; ++cc) {
        out[(size_t)cc * 5120] = f2bf(acc);
        acc += in[(size_t)cc * 4608];
    }
}

// ---------------- MFMA attention, split-phase staging ----------------------
__global__ __launch_bounds__(256)
void attn_kernel(const us* __restrict__ Qg, const us* __restrict__ Kg,
                 const us* __restrict__ VTg, const us* __restrict__ MTg,
                 us* __restrict__ ATT) {
    __shared__ __align__(16) us Qs[64 * 64];
    __shared__ __align__(16) us Ks[64 * 64];
    __shared__ __align__(16) us Vs[80 * 64];
    __shared__ __align__(16) us Ms[80 * 64];
    __shared__ __align__(16) us Sl[64 * 64];
    const int c = blockIdx.x, chain = blockIdx.y;
    const int b = chain >> 3, hh = chain & 7;
    const int tid = threadIdx.x;
    const int w = tid >> 6, l = tid & 63;
    const int l15 = l & 15, l4 = l >> 4;
    const int lrow = l >> 3, lg = l & 7;

#pragma unroll
    for (int r = 0; r < 2; ++r) {
        int slot = r * 4 + w;
        int row = slot * 8 + lrow;
        int g = lg ^ (row & 7);
        size_t grow = (size_t)((c * 64 + row) * 2 + b) * 512 + hh * 64 + g * 8;
        gload_lds16(Qg + grow, Qs + slot * 512);
        gload_lds16(Kg + grow, Ks + slot * 512);
    }
#pragma unroll
    for (int i = 0; i < 5; ++i) {
        int p = w * 5 + i;
        int s = p < 10 ? p : p - 10;
        int row = s * 8 + lrow;
        int g = lg ^ (row & 7);
        if (p < 10)
            gload_lds16(VTg + (size_t)(chain * 80 + row) * 2048 + c * 64 + g * 8,
                        Vs + s * 512);
        else
            gload_lds16(MTg + ((size_t)(chain * 32 + c) * 80 + row) * 64 + g * 8,
                        Ms + s * 512);
    }
    asm volatile("s_waitcnt vmcnt(5)" ::: "memory");
    __builtin_amdgcn_sched_barrier(0);
    __builtin_amdgcn_s_barrier();

    short8 qf[2];
    {
        int row = w * 16 + l15, p = l4 ^ (row & 7);
        qf[0] = *(const short8*)(Qs + row * 64 + p * 8);
        qf[1] = *(const short8*)(Qs + row * 64 + (p ^ 4) * 8);
    }
    short8 kf[4][2];
#pragma unroll
    for (int ni = 0; ni < 4; ++ni) {
        int row = ni * 16 + l15, p = l4 ^ (row & 7);
        kf[ni][0] = *(const short8*)(Ks + row * 64 + p * 8);
        kf[ni][1] = *(const short8*)(Ks + row * 64 + (p ^ 4) * 8);
    }
    const int ibase = w * 16 + l4 * 4;
#pragma unroll
    for (int ni = 0; ni < 4; ++ni) {
        floatx4 s = {0.f, 0.f, 0.f, 0.f};
        s = mfma_bf16(qf[0], kf[ni][0], s);
        s = mfma_bf16(qf[1], kf[ni][1], s);
        int col = ni * 16 + l15;
#pragma unroll
        for (int r = 0; r < 4; ++r) {
            int i = ibase + r;
            float v = (col <= i) ? s[r] : 0.f;
            Sl[i * 64 + (((col >> 3) ^ (i & 7)) * 8) + (col & 7)] = f2bf(v);
        }
    }
    short8 sf[2];
    {
        int ir = w * 16 + l15;  // rows written by this wave only
        sf[0] = *(const short8*)(Sl + ir * 64 + ((l4 ^ (ir & 7)) * 8));
        sf[1] = *(const short8*)(Sl + ir * 64 + (((4 + l4) ^ (ir & 7)) * 8));
    }
    __syncthreads();  // drains vmcnt(0): V,M staged by all waves

    short8 vf[5][2], mf[5][2];
#pragma unroll
    for (int ni = 0; ni < 5; ++ni) {
        int row = ni * 16 + l15, p = l4 ^ (row & 7);
        vf[ni][0] = *(const short8*)(Vs + row * 64 + p * 8);
        vf[ni][1] = *(const short8*)(Vs + row * 64 + (p ^ 4) * 8);
        mf[ni][0] = *(const short8*)(Ms + row * 64 + p * 8);
        mf[ni][1] = *(const short8*)(Ms + row * 64 + (p ^ 4) * 8);
    }
    floatx4 acc[5];
#pragma unroll
    for (int ni = 0; ni < 5; ++ni) {
        floatx4 a = {0.f, 0.f, 0.f, 0.f};
        a = mfma_bf16(sf[0], vf[ni][0], a);
        a = mfma_bf16(sf[1], vf[ni][1], a);
        a = mfma_bf16(qf[0], mf[ni][0], a);
        a = mfma_bf16(qf[1], mf[ni][1], a);
        acc[ni] = a;
    }
    float fac[4];
#pragma unroll
    for (int r = 0; r < 4; ++r) {
        float den = __shfl(acc[4][r], l & 48, 64);
        fac[r] = SCALE / (SCALE * den + EPS);
    }
#pragma unroll
    for (int ni = 0; ni < 4; ++ni)
#pragma unroll
        for (int r = 0; r < 4; ++r) {
            int i = ibase + r;
            ATT[((size_t)((c * 64 + i) * 2 + b)) * 512 + hh * 64 + ni * 16 + l15] =
                f2bf(acc[ni][r] * fac[r]);
        }
}

// ---------------- fused Wo GEMM + residual + LayerNorm ---------------------
__global__ __launch_bounds__(256)
void wo_ln_kernel(const us* __restrict__ ATT, const us* __restrict__ WoT,
                  const float* __restrict__ h, const float* __restrict__ gamma,
                  const float* __restrict__ beta, float* __restrict__ out) {
    __shared__ __align__(16) us As[2][16 * 32];
    __shared__ __align__(16) us Bs[2][512 * 32];
    __shared__ float redS[4][16];
    __shared__ float redQ[4][16];
    __shared__ float mml[16], rsl[16];
    const int tid = threadIdx.x;
    const int w = tid >> 6, l = tid & 63;
    const int l15 = l & 15, l4 = l >> 4;
    const int m0 = blockIdx.x * 16, wn = w * 128;
    floatx4 acc[8];
#pragma unroll
    for (int j = 0; j < 8; ++j)
#pragma unroll
        for (int e = 0; e < 4; ++e) acc[j][e] = 0.f;

    auto STAGE = [&](int buf, int kt) {
#pragma unroll
        for (int r = 0; r < 8; ++r) {
            int slot = r * 4 + w;
            int row = slot * 16 + (l >> 2);
            int g = (l & 3) ^ (row & 3);
            gload_lds16(WoT + (size_t)row * 512 + kt + g * 8, &Bs[buf][slot * 512]);
        }
        if (w == 0) {
            int row = l >> 2;
            int g = (l & 3) ^ (row & 3);
            gload_lds16(ATT + (size_t)(m0 + row) * 512 + kt + g * 8, &As[buf][0]);
        }
    };

    STAGE(0, 0);
    __syncthreads();
    for (int t = 0; t < 16; ++t) {
        int cur = t & 1;
        if (t < 15) STAGE(cur ^ 1, (t + 1) * 32);
        short8 af, bf[8];
        {
            int row = l15, p = l4 ^ (row & 3);
            af = *(const short8*)(&As[cur][row * 32 + p * 8]);
        }
#pragma unroll
        for (int ni = 0; ni < 8; ++ni) {
            int row = wn + ni * 16 + l15, p = l4 ^ (row & 3);
            bf[ni] = *(const short8*)(&Bs[cur][row * 32 + p * 8]);
        }
#pragma unroll
        for (int ni = 0; ni < 8; ++ni)
            acc[ni] = mfma_bf16(af, bf[ni], acc[ni]);
        __syncthreads();
    }

#pragma unroll
    for (int r = 0; r < 4; ++r) {
        int row = l4 * 4 + r;
        const float* hrow = h + (size_t)(m0 + row) * 512 + wn + l15;
        float s = 0.f, q = 0.f;
#pragma unroll
        for (int ni = 0; ni < 8; ++ni) {
            float x = acc[ni][r] + hrow[ni * 16];
            acc[ni][r] = x;
            s += x;
            q = fmaf(x, x, q);
        }
#pragma unroll
        for (int off = 1; off <= 8; off <<= 1) {
            s += __shfl_xor(s, off, 64);
            q += __shfl_xor(q, off, 64);
        }
        if (l15 == 0) { redS[w][row] = s; redQ[w][row] = q; }
    }
    __syncthreads();
    if (tid < 16) {
        float s = redS[0][tid] + redS[1][tid] + redS[2][tid] + redS[3][tid];
        float q = redQ[0][tid] + redQ[1][tid] + redQ[2][tid] + redQ[3][tid];
        float mean = s * (1.f / 512);
        float var = q * (1.f / 512) - mean * mean;
        mml[tid] = mean;
        rsl[tid] = rsqrtf(var + LN_EPS);
    }
    __syncthreads();
#pragma unroll
    for (int r = 0; r < 4; ++r) {
        int row = l4 * 4 + r;
        float mean = mml[row], rstd = rsl[row];
#pragma unroll
        for (int ni = 0; ni < 8; ++ni) {
            int col = wn + ni * 16 + l15;
            out[(size_t)(m0 + row) * 512 + col] =
                (acc[ni][r] - mean) * rstd * gamma[col] + beta[col];
        }
    }
}

extern "C" void kernel_launch(void* const* d_in, const int* in_sizes, int n_in,
                              void* d_out, int out_size, void* d_ws, size_t ws_size,
                              hipStream_t stream) {
    const float* h = (const float*)d_in[0];
    const float* Wq = (const float*)d_in[1];
    const float* Wkv = (const float*)d_in[2];
    const float* Wo = (const float*)d_in[3];
    const float* gamma = (const float*)d_in[4];
    const float* beta = (const float*)d_in[5];

    char* ws = (char*)d_ws;
    us* Qg      = (us*)(ws + 0);          //  4 MB
    us* Kg      = (us*)(ws + 4194304);    //  4 MB
    us* VTg     = (us*)(ws + 12582912);   //  5.25 MB [16][80][2048]
    us* ATT     = (us*)(ws + 17825792);   //  4 MB
    us* WoT     = (us*)(ws + 22020096);   //  0.5 MB
    us* MTg     = (us*)(ws + 22544384);   //  5.25 MB [16][32][80][64]
    us* hB      = (us*)(ws + 27787264);   //  4 MB
    us* WqkvT   = (us*)(ws + 31981568);   //  1.5 MB
    float* KVc  = (float*)(ws + 33554432);//  9.44 MB

    dim3 blk(256);
    pack_kernel<<<2336, blk, 0, stream>>>(h, Wq, Wkv, Wo, hB, WqkvT, WoT, VTg);
    qkv_gemm<<<dim3(12, 32), blk, 0, stream>>>(hB, WqkvT, Qg, Kg, VTg, KVc);
    cumsum_kernel<<<dim3(16, 17), blk, 0, stream>>>(KVc, MTg);
    attn_kernel<<<dim3(32, 16), blk, 0, stream>>>(Qg, Kg, VTg, MTg, ATT);
    wo_ln_kernel<<<256, blk, 0, stream>>>(ATT, WoT, h, gamma, beta, (float*)d_out);
}

// Round 10
// 134.478 us; speedup vs baseline: 1.0054x; 1.0054x over previous
//
#include <hip/hip_runtime.h>
#include <hip/hip_bf16.h>
#include <math.h>

#define SCALE 0.125f
#define EPS 1e-5f
#define LN_EPS 1e-5f

typedef short short8 __attribute__((ext_vector_type(8)));
typedef float floatx4 __attribute__((ext_vector_type(4)));
typedef unsigned short us;

__device__ __forceinline__ float elu1(float x) { return x > 0.f ? x + 1.f : __expf(x); }
__device__ __forceinline__ us f2bf(float f) {
    __hip_bfloat16 b = __float2bfloat16(f);
    return __builtin_bit_cast(us, b);
}
__device__ __forceinline__ void gload_lds16(const void* g, void* lds) {
    __builtin_amdgcn_global_load_lds(
        (const __attribute__((address_space(1))) unsigned int*)g,
        (__attribute__((address_space(3))) unsigned int*)lds, 16, 0, 0);
}
__device__ __forceinline__ floatx4 mfma_bf16(short8 a, short8 b, floatx4 c) {
    return __builtin_amdgcn_mfma_f32_16x16x32_bf16(a, b, c, 0, 0, 0);
}

// ---------------- pack: h->bf16 (coalesced), LDS-tiled weight transposes ----
__global__ __launch_bounds__(256)
void pack_kernel(const float* __restrict__ h, const float* __restrict__ Wq,
                 const float* __restrict__ Wkv, const float* __restrict__ Wo,
                 us* __restrict__ hB, us* __restrict__ WqkvT, us* __restrict__ WoT,
                 us* __restrict__ VTg) {
    const int bid = blockIdx.x, tid = threadIdx.x;
    if (bid < 2048) {
        int idx = bid * 1024 + tid * 4;
        float4 v = *(const float4*)(h + idx);
        ushort4 o;
        o.x = f2bf(v.x); o.y = f2bf(v.y); o.z = f2bf(v.z); o.w = f2bf(v.w);
        *(ushort4*)(hB + idx) = o;
        return;
    }
    if (bid < 2304) {
        __shared__ us T[64][72];
        const float* src; int ld, n0s, k0; us* dst;
        if (bid < 2240) {
            int t2 = bid - 2048;           // Wqkv: 24 n-tiles x 8 k-tiles
            int nt = t2 % 24, kt = t2 / 24;
            int n0 = nt * 64; k0 = kt * 64;
            if (n0 < 512) { src = Wq; ld = 512; n0s = n0; }
            else          { src = Wkv; ld = 1024; n0s = n0 - 512; }
            dst = WqkvT + (size_t)n0 * 512;
        } else {
            int t2 = bid - 2240;           // Wo: 8 x 8
            int nt = t2 & 7, kt = t2 >> 3;
            src = Wo; ld = 512; n0s = nt * 64; k0 = kt * 64;
            dst = WoT + (size_t)(nt * 64) * 512;
        }
        {
            int k = tid >> 2, cs = (tid & 3) * 16;
            const float* p = src + (size_t)(k0 + k) * ld + n0s + cs;
#pragma unroll
            for (int q = 0; q < 4; ++q) {
                float4 v = *(const float4*)(p + q * 4);
                T[k][cs + q * 4 + 0] = f2bf(v.x);
                T[k][cs + q * 4 + 1] = f2bf(v.y);
                T[k][cs + q * 4 + 2] = f2bf(v.z);
                T[k][cs + q * 4 + 3] = f2bf(v.w);
            }
        }
        __syncthreads();
        {
            int n = tid >> 2, ks = (tid & 3) * 16;
            __align__(16) us tmp[16];
#pragma unroll
            for (int j = 0; j < 16; ++j) tmp[j] = T[ks + j][n];
            us* po = dst + (size_t)n * 512 + k0 + ks;
            *(uint4*)(po) = *(uint4*)(tmp);
            *(uint4*)(po + 8) = *(uint4*)(tmp + 8);
        }
        return;
    }
    {   // VTg ones row (row 64 of each chain)
        int e = (bid - 2304) * 1024 + tid * 4;
        int chain = e >> 11, s = e & 2047;
        ushort4 o; o.x = 0x3f80; o.y = 0x3f80; o.z = 0x3f80; o.w = 0x3f80;
        *(ushort4*)(VTg + ((size_t)(chain * 80 + 64)) * 2048 + s) = o;
    }
}

// ---------------- QKV GEMM: BM=64, dbuf, XCD-clustered m-rows --------------
// XCD swizzle: each XCD owns 8 contiguous m-tiles x all 12 n-tiles, so the
// 512KB A-slice + 1.5MB B stay L2-resident per XCD (T1, m192).
__global__ __launch_bounds__(256)
void qkv_gemm(const us* __restrict__ A, const us* __restrict__ BT,
              us* __restrict__ Qg, us* __restrict__ Kg, us* __restrict__ VTg) {
    __shared__ __align__(16) us As[2][64 * 32];
    __shared__ __align__(16) us Bs[2][128 * 32];
    const int tid = threadIdx.x;
    const int w = tid >> 6, l = tid & 63;
    const int l15 = l & 15, l4 = l >> 4;
    // grid = 768 flat; remap: xcd g&7 -> 8 m-tiles x 12 n-tiles
    const int g = blockIdx.x;
    const int xcd = g & 7, idx = g >> 3;          // idx 0..95
    const int mt = xcd * 8 + idx / 12;            // 0..63
    const int nt = idx % 12;                      // 0..11
    const int m0 = mt * 64, n0 = nt * 128;
    const int wm = (w >> 1) * 32, wn = (w & 1) * 64;
    floatx4 acc[2][4];
#pragma unroll
    for (int i = 0; i < 2; ++i)
#pragma unroll
        for (int j = 0; j < 4; ++j)
#pragma unroll
            for (int e = 0; e < 4; ++e) acc[i][j][e] = 0.f;

    auto STAGE = [&](int buf, int kt) {
        {   // A: 64 rows, one instr per wave
            int row = w * 16 + (l >> 2);
            int gg = (l & 3) ^ (row & 3);
            gload_lds16(A + (size_t)(m0 + row) * 512 + kt + gg * 8, &As[buf][w * 512]);
        }
#pragma unroll
        for (int r = 0; r < 2; ++r) {   // B: 128 rows, two instrs per wave
            int slot = r * 4 + w;
            int row = slot * 16 + (l >> 2);
            int gg = (l & 3) ^ (row & 3);
            gload_lds16(BT + (size_t)(n0 + row) * 512 + kt + gg * 8, &Bs[buf][slot * 512]);
        }
    };

    STAGE(0, 0);
    __syncthreads();
    for (int t = 0; t < 16; ++t) {
        int cur = t & 1;
        if (t < 15) STAGE(cur ^ 1, (t + 1) * 32);
        short8 a[2], b[4];
#pragma unroll
        for (int mi = 0; mi < 2; ++mi) {
            int row = wm + mi * 16 + l15;
            int p = l4 ^ (row & 3);
            a[mi] = *(const short8*)(&As[cur][row * 32 + p * 8]);
        }
#pragma unroll
        for (int ni = 0; ni < 4; ++ni) {
            int row = wn + ni * 16 + l15;
            int p = l4 ^ (row & 3);
            b[ni] = *(const short8*)(&Bs[cur][row * 32 + p * 8]);
        }
#pragma unroll
        for (int mi = 0; mi < 2; ++mi)
#pragma unroll
            for (int ni = 0; ni < 4; ++ni)
                acc[mi][ni] = mfma_bf16(a[mi], b[ni], acc[mi][ni]);
        __syncthreads();
    }
    const int region = nt >> 2;  // 0=Q 1=K 2=V
    const int cb = (nt & 3) * 128;
    if (region < 2) {
        us* outp = region == 0 ? Qg : Kg;
#pragma unroll
        for (int mi = 0; mi < 2; ++mi)
#pragma unroll
            for (int ni = 0; ni < 4; ++ni)
#pragma unroll
                for (int r = 0; r < 4; ++r) {
                    int row = m0 + wm + mi * 16 + l4 * 4 + r;
                    int col = cb + wn + ni * 16 + l15;
                    outp[(size_t)row * 512 + col] = f2bf(elu1(acc[mi][ni][r]));
                }
    } else {
        // V: write transposed VTg[chain][d][s], s-pairs packed into 4B stores
        const int hh = (nt & 3) * 2 + (w & 1);
#pragma unroll
        for (int mi = 0; mi < 2; ++mi) {
            int row0 = m0 + wm + mi * 16 + l4 * 4;  // even, %4==0
            int s0 = row0 >> 1;
#pragma unroll
            for (int ni = 0; ni < 4; ++ni) {
                int d = ni * 16 + l15;
#pragma unroll
                for (int b = 0; b < 2; ++b) {
                    unsigned int pk = (unsigned int)f2bf(acc[mi][ni][b]) |
                                      ((unsigned int)f2bf(acc[mi][ni][2 + b]) << 16);
                    *(unsigned int*)(VTg + ((size_t)((b * 8 + hh) * 80 + d)) * 2048 + s0) = pk;
                }
            }
        }
    }
}

// ---------------- per-chunk: C = [V^T;1] K^T, XCD-clustered chains ---------
__global__ __launch_bounds__(256)
void chunk_kv_kernel(const us* __restrict__ Kg, const us* __restrict__ VTg,
                     float* __restrict__ KVc) {
    __shared__ __align__(16) us VT_l[80 * 64];
    __shared__ __align__(16) us KT_l[64 * 72];
    // grid = 512 flat; xcd owns 2 chains x 32 chunks (VTg 640KB L2-resident)
    const int gid = blockIdx.x;
    const int xcd = gid & 7, idx = gid >> 3;      // idx 0..63
    const int chain = xcd * 2 + (idx >> 5);
    const int c = idx & 31;
    const int b = chain >> 3, hh = chain & 7;
    const int tid = threadIdx.x;
    const int w = tid >> 6, l = tid & 63;
    const int lrow = l >> 3, lg = l & 7;
#pragma unroll
    for (int r = 0; r < 3; ++r) {
        int slot = r * 4 + w;
        if (slot < 10) {
            int row = slot * 8 + lrow;
            int g = lg ^ (row & 7);
            gload_lds16(VTg + (size_t)(chain * 80 + row) * 2048 + c * 64 + g * 8,
                        VT_l + slot * 512);
        }
    }
#pragma unroll
    for (int gi = 0; gi < 2; ++gi) {
        int g = w + gi * 4;
        __align__(16) us kk[8];
#pragma unroll
        for (int e = 0; e < 8; ++e)
            kk[e] = Kg[(size_t)((c * 64 + g * 8 + e) * 2 + b) * 512 + hh * 64 + l];
        *(uint4*)(KT_l + l * 72 + g * 8) = *(uint4*)kk;
    }
    __syncthreads();
    const int l15 = l & 15, l4 = l >> 4;
    short8 af[5][2], bfr[2];
#pragma unroll
    for (int mi = 0; mi < 5; ++mi) {
        int row = mi * 16 + l15;
        int p = l4 ^ (row & 7);
        af[mi][0] = *(const short8*)(VT_l + row * 64 + p * 8);
        af[mi][1] = *(const short8*)(VT_l + row * 64 + (p ^ 4) * 8);
    }
    {
        int row = w * 16 + l15;
        bfr[0] = *(const short8*)(KT_l + row * 72 + l4 * 8);
        bfr[1] = *(const short8*)(KT_l + row * 72 + 32 + l4 * 8);
    }
    float* out = KVc + (size_t)(chain * 32 + c) * 4608;
#pragma unroll
    for (int mi = 0; mi < 5; ++mi) {
        floatx4 a = {0.f, 0.f, 0.f, 0.f};
        a = mfma_bf16(af[mi][0], bfr[0], a);
        a = mfma_bf16(af[mi][1], bfr[1], a);
#pragma unroll
        for (int r = 0; r < 4; ++r) {
            int row = mi * 16 + l4 * 4 + r;
            if (row < 65) out[row * 64 + w * 16 + l15] = a[r];
        }
    }
}

// ---------------- exclusive prefix over chunks -> bf16 MTg -----------------
__global__ __launch_bounds__(256)
void cumsum_kernel(const float* __restrict__ KVc, us* __restrict__ MTg) {
    const int chain = blockIdx.x, rg = blockIdx.y;
    const int row = rg * 4 + (threadIdx.x >> 6), col = threadIdx.x & 63;
    const float* in = KVc + (size_t)chain * 32 * 4608 + row * 64 + col;
    us* out = MTg + ((size_t)chain * 32 * 80 + row) * 64 + col;
    float acc = 0.f;
#pragma unroll 4
    for (int cc = 0; cc < 32; ++cc) {
        out[(size_t)cc * 5120] = f2bf(acc);
        acc += in[(size_t)cc * 4608];
    }
}

// ---------------- MFMA attention, split-phase, XCD-clustered chains --------
__global__ __launch_bounds__(256)
void attn_kernel(const us* __restrict__ Qg, const us* __restrict__ Kg,
                 const us* __restrict__ VTg, const us* __restrict__ MTg,
                 us* __restrict__ ATT) {
    __shared__ __align__(16) us Qs[64 * 64];
    __shared__ __align__(16) us Ks[64 * 64];
    __shared__ __align__(16) us Vs[80 * 64];
    __shared__ __align__(16) us Ms[80 * 64];
    __shared__ __align__(16) us Sl[64 * 64];
    const int gid = blockIdx.x;
    const int xcd = gid & 7, idx = gid >> 3;      // idx 0..63
    const int chain = xcd * 2 + (idx >> 5);
    const int c = idx & 31;
    const int b = chain >> 3, hh = chain & 7;
    const int tid = threadIdx.x;
    const int w = tid >> 6, l = tid & 63;
    const int l15 = l & 15, l4 = l >> 4;
    const int lrow = l >> 3, lg = l & 7;

#pragma unroll
    for (int r = 0; r < 2; ++r) {
        int slot = r * 4 + w;
        int row = slot * 8 + lrow;
        int g = lg ^ (row & 7);
        size_t grow = (size_t)((c * 64 + row) * 2 + b) * 512 + hh * 64 + g * 8;
        gload_lds16(Qg + grow, Qs + slot * 512);
        gload_lds16(Kg + grow, Ks + slot * 512);
    }
#pragma unroll
    for (int i = 0; i < 5; ++i) {
        int p = w * 5 + i;
        int s = p < 10 ? p : p - 10;
        int row = s * 8 + lrow;
        int g = lg ^ (row & 7);
        if (p < 10)
            gload_lds16(VTg + (size_t)(chain * 80 + row) * 2048 + c * 64 + g * 8,
                        Vs + s * 512);
        else
            gload_lds16(MTg + ((size_t)(chain * 32 + c) * 80 + row) * 64 + g * 8,
                        Ms + s * 512);
    }
    asm volatile("s_waitcnt vmcnt(5)" ::: "memory");
    __builtin_amdgcn_sched_barrier(0);
    __builtin_amdgcn_s_barrier();

    short8 qf[2];
    {
        int row = w * 16 + l15, p = l4 ^ (row & 7);
        qf[0] = *(const short8*)(Qs + row * 64 + p * 8);
        qf[1] = *(const short8*)(Qs + row * 64 + (p ^ 4) * 8);
    }
    short8 kf[4][2];
#pragma unroll
    for (int ni = 0; ni < 4; ++ni) {
        int row = ni * 16 + l15, p = l4 ^ (row & 7);
        kf[ni][0] = *(const short8*)(Ks + row * 64 + p * 8);
        kf[ni][1] = *(const short8*)(Ks + row * 64 + (p ^ 4) * 8);
    }
    const int ibase = w * 16 + l4 * 4;
#pragma unroll
    for (int ni = 0; ni < 4; ++ni) {
        floatx4 s = {0.f, 0.f, 0.f, 0.f};
        s = mfma_bf16(qf[0], kf[ni][0], s);
        s = mfma_bf16(qf[1], kf[ni][1], s);
        int col = ni * 16 + l15;
#pragma unroll
        for (int r = 0; r < 4; ++r) {
            int i = ibase + r;
            float v = (col <= i) ? s[r] : 0.f;
            Sl[i * 64 + (((col >> 3) ^ (i & 7)) * 8) + (col & 7)] = f2bf(v);
        }
    }
    short8 sf[2];
    {
        int ir = w * 16 + l15;  // rows written by this wave only
        sf[0] = *(const short8*)(Sl + ir * 64 + ((l4 ^ (ir & 7)) * 8));
        sf[1] = *(const short8*)(Sl + ir * 64 + (((4 + l4) ^ (ir & 7)) * 8));
    }
    __syncthreads();  // drains vmcnt(0): V,M staged by all waves

    short8 vf[5][2], mf[5][2];
#pragma unroll
    for (int ni = 0; ni < 5; ++ni) {
        int row = ni * 16 + l15, p = l4 ^ (row & 7);
        vf[ni][0] = *(const short8*)(Vs + row * 64 + p * 8);
        vf[ni][1] = *(const short8*)(Vs + row * 64 + (p ^ 4) * 8);
        mf[ni][0] = *(const short8*)(Ms + row * 64 + p * 8);
        mf[ni][1] = *(const short8*)(Ms + row * 64 + (p ^ 4) * 8);
    }
    floatx4 acc[5];
#pragma unroll
    for (int ni = 0; ni < 5; ++ni) {
        floatx4 a = {0.f, 0.f, 0.f, 0.f};
        a = mfma_bf16(sf[0], vf[ni][0], a);
        a = mfma_bf16(sf[1], vf[ni][1], a);
        a = mfma_bf16(qf[0], mf[ni][0], a);
        a = mfma_bf16(qf[1], mf[ni][1], a);
        acc[ni] = a;
    }
    float fac[4];
#pragma unroll
    for (int r = 0; r < 4; ++r) {
        float den = __shfl(acc[4][r], l & 48, 64);
        fac[r] = SCALE / (SCALE * den + EPS);
    }
#pragma unroll
    for (int ni = 0; ni < 4; ++ni)
#pragma unroll
        for (int r = 0; r < 4; ++r) {
            int i = ibase + r;
            ATT[((size_t)((c * 64 + i) * 2 + b)) * 512 + hh * 64 + ni * 16 + l15] =
                f2bf(acc[ni][r] * fac[r]);
        }
}

// ---------------- fused Wo GEMM + residual + LayerNorm ---------------------
__global__ __launch_bounds__(256)
void wo_ln_kernel(const us* __restrict__ ATT, const us* __restrict__ WoT,
                  const float* __restrict__ h, const float* __restrict__ gamma,
                  const float* __restrict__ beta, float* __restrict__ out) {
    __shared__ __align__(16) us As[2][16 * 32];
    __shared__ __align__(16) us Bs[2][512 * 32];
    __shared__ float redS[4][16];
    __shared__ float redQ[4][16];
    __shared__ float mml[16], rsl[16];
    const int tid = threadIdx.x;
    const int w = tid >> 6, l = tid & 63;
    const int l15 = l & 15, l4 = l >> 4;
    const int m0 = blockIdx.x * 16, wn = w * 128;
    floatx4 acc[8];
#pragma unroll
    for (int j = 0; j < 8; ++j)
#pragma unroll
        for (int e = 0; e < 4; ++e) acc[j][e] = 0.f;

    auto STAGE = [&](int buf, int kt) {
#pragma unroll
        for (int r = 0; r < 8; ++r) {
            int slot = r * 4 + w;
            int row = slot * 16 + (l >> 2);
            int g = (l & 3) ^ (row & 3);
            gload_lds16(WoT + (size_t)row * 512 + kt + g * 8, &Bs[buf][slot * 512]);
        }
        if (w == 0) {
            int row = l >> 2;
            int g = (l & 3) ^ (row & 3);
            gload_lds16(ATT + (size_t)(m0 + row) * 512 + kt + g * 8, &As[buf][0]);
        }
    };

    STAGE(0, 0);
    __syncthreads();
    for (int t = 0; t < 16; ++t) {
        int cur = t & 1;
        if (t < 15) STAGE(cur ^ 1, (t + 1) * 32);
        short8 af, bf[8];
        {
            int row = l15, p = l4 ^ (row & 3);
            af = *(const short8*)(&As[cur][row * 32 + p * 8]);
        }
#pragma unroll
        for (int ni = 0; ni < 8; ++ni) {
            int row = wn + ni * 16 + l15, p = l4 ^ (row & 3);
            bf[ni] = *(const short8*)(&Bs[cur][row * 32 + p * 8]);
        }
#pragma unroll
        for (int ni = 0; ni < 8; ++ni)
            acc[ni] = mfma_bf16(af, bf[ni], acc[ni]);
        __syncthreads();
    }

#pragma unroll
    for (int r = 0; r < 4; ++r) {
        int row = l4 * 4 + r;
        const float* hrow = h + (size_t)(m0 + row) * 512 + wn + l15;
        float s = 0.f, q = 0.f;
#pragma unroll
        for (int ni = 0; ni < 8; ++ni) {
            float x = acc[ni][r] + hrow[ni * 16];
            acc[ni][r] = x;
            s += x;
            q = fmaf(x, x, q);
        }
#pragma unroll
        for (int off = 1; off <= 8; off <<= 1) {
            s += __shfl_xor(s, off, 64);
            q += __shfl_xor(q, off, 64);
        }
        if (l15 == 0) { redS[w][row] = s; redQ[w][row] = q; }
    }
    __syncthreads();
    if (tid < 16) {
        float s = redS[0][tid] + redS[1][tid] + redS[2][tid] + redS[3][tid];
        float q = redQ[0][tid] + redQ[1][tid] + redQ[2][tid] + redQ[3][tid];
        float mean = s * (1.f / 512);
        float var = q * (1.f / 512) - mean * mean;
        mml[tid] = mean;
        rsl[tid] = rsqrtf(var + LN_EPS);
    }
    __syncthreads();
#pragma unroll
    for (int r = 0; r < 4; ++r) {
        int row = l4 * 4 + r;
        float mean = mml[row], rstd = rsl[row];
#pragma unroll
        for (int ni = 0; ni < 8; ++ni) {
            int col = wn + ni * 16 + l15;
            out[(size_t)(m0 + row) * 512 + col] =
                (acc[ni][r] - mean) * rstd * gamma[col] + beta[col];
        }
    }
}

extern "C" void kernel_launch(void* const* d_in, const int* in_sizes, int n_in,
                              void* d_out, int out_size, void* d_ws, size_t ws_size,
                              hipStream_t stream) {
    const float* h = (const float*)d_in[0];
    const float* Wq = (const float*)d_in[1];
    const float* Wkv = (const float*)d_in[2];
    const float* Wo = (const float*)d_in[3];
    const float* gamma = (const float*)d_in[4];
    const float* beta = (const float*)d_in[5];

    char* ws = (char*)d_ws;
    us* Qg      = (us*)(ws + 0);          //  4 MB
    us* Kg      = (us*)(ws + 4194304);    //  4 MB
    us* VTg     = (us*)(ws + 12582912);   //  5.25 MB [16][80][2048]
    us* ATT     = (us*)(ws + 17825792);   //  4 MB
    us* WoT     = (us*)(ws + 22020096);   //  0.5 MB
    us* MTg     = (us*)(ws + 22544384);   //  5.25 MB [16][32][80][64]
    us* hB      = (us*)(ws + 27787264);   //  4 MB
    us* WqkvT   = (us*)(ws + 31981568);   //  1.5 MB
    float* KVc  = (float*)(ws + 33554432);//  9.44 MB

    dim3 blk(256);
    pack_kernel<<<2336, blk, 0, stream>>>(h, Wq, Wkv, Wo, hB, WqkvT, WoT, VTg);
    qkv_gemm<<<768, blk, 0, stream>>>(hB, WqkvT, Qg, Kg, VTg);
    chunk_kv_kernel<<<512, blk, 0, stream>>>(Kg, VTg, KVc);
    cumsum_kernel<<<dim3(16, 17), blk, 0, stream>>>(KVc, MTg);
    attn_kernel<<<512, blk, 0, stream>>>(Qg, Kg, VTg, MTg, ATT);
    wo_ln_kernel<<<256, blk, 0, stream>>>(ATT, WoT, h, gamma, beta, (float*)d_out);
}